// Round 7
// baseline (579.964 us; speedup 1.0000x reference)
//
#include <hip/hip_runtime.h>
#include <hip/hip_bf16.h>
#include <math.h>

typedef __bf16 bf16x8 __attribute__((ext_vector_type(8)));
typedef __bf16 bf16x4 __attribute__((ext_vector_type(4)));
typedef unsigned short u16x8 __attribute__((ext_vector_type(8)));
typedef float  f32x4  __attribute__((ext_vector_type(4)));

constexpr int kS   = 2048;
constexpr int kH   = 4096;
constexpr int kNH  = 32;
constexpr int kNKV = 8;
constexpr int kHD  = 128;
constexpr int kQKV = kH + 2 * kNKV * kHD;   // 6144: [Q 4096 | K 1024 | V 1024]
constexpr int kKOff = kH;                    // 4096
constexpr int kVOff = kH + kNKV * kHD;       // 5120

// ---------------------------------------------------------------- generic cast
__global__ void cast_bf16(const float* __restrict__ in, __bf16* __restrict__ out, int n4) {
    int i = blockIdx.x * blockDim.x + threadIdx.x;
    if (i < n4) {
        float4 f = ((const float4*)in)[i];
        bf16x4 o;
        o[0] = (__bf16)f.x; o[1] = (__bf16)f.y; o[2] = (__bf16)f.z; o[3] = (__bf16)f.w;
        ((bf16x4*)out)[i] = o;
    }
}

// ---------------------------------------------------------------- fused cast: x -> xb, wq|wk|wv -> wqkv
__global__ void cast_all(const float* __restrict__ x, const float* __restrict__ wq,
                         const float* __restrict__ wk, const float* __restrict__ wv,
                         __bf16* __restrict__ xb, __bf16* __restrict__ wqkv) {
    int i = blockIdx.x * 256 + threadIdx.x;
    float4 f;
    __bf16* dst;
    int di;
    if (i < (1 << 21)) {
        f = ((const float4*)x)[i];
        dst = xb; di = i;
    } else {
        int j = i - (1 << 21);
        const float4* s = (j < (1 << 22)) ? ((const float4*)wq + j)
                        : (j < (5 << 20)) ? ((const float4*)wk + (j - (1 << 22)))
                                          : ((const float4*)wv + (j - (5 << 20)));
        f = *s;
        dst = wqkv; di = j;
    }
    bf16x4 o;
    o[0] = (__bf16)f.x; o[1] = (__bf16)f.y; o[2] = (__bf16)f.z; o[3] = (__bf16)f.w;
    ((bf16x4*)dst)[di] = o;
}

// ---------------------------------------------------------------- NT GEMM, BK=64, XOR-swizzled LDS
// Wave column tiles remapped to jt = {0,1,4,5}/{2,3,6,7} so rope pairs (d, d+64)
// are lane-local; ROPE=true applies RoPE (+ 1/sqrt(128) on Q) in the epilogue.
constexpr int BM = 128, BN = 128, BK = 64;

__device__ inline void gld16(const __bf16* g, __bf16* l) {
    __builtin_amdgcn_global_load_lds((const __attribute__((address_space(1))) void*)g,
                                     (__attribute__((address_space(3))) void*)l, 16, 0, 0);
}

template <typename OutT, bool ROPE>
__global__ __launch_bounds__(256) void gemm_nt(const __bf16* __restrict__ A,
                                               const __bf16* __restrict__ B,
                                               OutT* __restrict__ C,
                                               int M, int N, int K) {
    __shared__ __align__(16) __bf16 As[BM * BK];   // 16 KB
    __shared__ __align__(16) __bf16 Bs[BN * BK];   // 16 KB
    const int tid  = threadIdx.x;
    const int w    = tid >> 6, lane = tid & 63;
    const int m0   = blockIdx.y * BM, n0 = blockIdx.x * BN;
    const int wm   = (w >> 1) * 64;
    const int wn2  = (w & 1);
    const int lr   = lane & 15, g8 = lane >> 4;

    int jt[4];
#pragma unroll
    for (int j = 0; j < 4; j++) jt[j] = wn2 * 2 + (j & 1) + ((j >> 1) << 2);

    const int l3 = lane >> 3;
    const int lc = (lane & 7) ^ l3;
    const __bf16 *gA[4], *gB[4];
    __bf16 *lA[4], *lB[4];
#pragma unroll
    for (int c = 0; c < 4; c++) {
        int G = w * 4 + c;
        gA[c] = A + (size_t)(m0 + G * 8 + l3) * K + lc * 8;
        gB[c] = B + (size_t)(n0 + G * 8 + l3) * K + lc * 8;
        lA[c] = As + G * 512;
        lB[c] = Bs + G * 512;
    }

    f32x4 acc[4][4];
#pragma unroll
    for (int i = 0; i < 4; i++)
#pragma unroll
        for (int j = 0; j < 4; j++) acc[i][j] = (f32x4)(0.f);

    for (int k0 = 0; k0 < K; k0 += BK) {
#pragma unroll
        for (int c = 0; c < 4; c++) {
            gld16(gA[c] + k0, lA[c]);
            gld16(gB[c] + k0, lB[c]);
        }
        __syncthreads();

        const int rx = lr & 7;
#pragma unroll
        for (int kc = 0; kc < 2; kc++) {
            bf16x8 af[4], bfr[4];
#pragma unroll
            for (int i = 0; i < 4; i++)
                af[i]  = *(const bf16x8*)&As[(wm + i * 16 + lr) * BK + (((kc * 4 + g8) ^ rx) * 8)];
#pragma unroll
            for (int j = 0; j < 4; j++)
                bfr[j] = *(const bf16x8*)&Bs[(jt[j] * 16 + lr) * BK + (((kc * 4 + g8) ^ rx) * 8)];
#pragma unroll
            for (int i = 0; i < 4; i++)
#pragma unroll
                for (int j = 0; j < 4; j++)
                    acc[i][j] = __builtin_amdgcn_mfma_f32_16x16x32_bf16(af[i], bfr[j], acc[i][j], 0, 0, 0);
        }
        __syncthreads();
    }

    const int cr = g8 * 4, cc = lr;

    if (ROPE && n0 < kVOff) {
        // rope pairs: (acc[i][p], acc[i][p+2]) = cols (d, d+64), d = wn2*32 + p*16 + cc
        const float qs = (n0 < kKOff) ? 0.088388347648318447f : 1.0f;
        float invf[2];
#pragma unroll
        for (int p = 0; p < 2; p++)
            invf[p] = powf(500000.0f, -(float)(wn2 * 32 + p * 16 + cc) * (1.0f / 64.0f));
#pragma unroll
        for (int i = 0; i < 4; i++)
#pragma unroll
            for (int reg = 0; reg < 4; reg++) {
                float s = (float)(m0 + wm + i * 16 + cr + reg);
#pragma unroll
                for (int p = 0; p < 2; p++) {
                    float sn, cs;
                    sincosf(s * invf[p], &sn, &cs);
                    float a = acc[i][p][reg], b = acc[i][p + 2][reg];
                    acc[i][p][reg]     = (a * cs - b * sn) * qs;
                    acc[i][p + 2][reg] = (b * cs + a * sn) * qs;
                }
            }
    }

#pragma unroll
    for (int i = 0; i < 4; i++)
#pragma unroll
        for (int j = 0; j < 4; j++) {
            OutT* Cp = C + (size_t)(m0 + wm + i * 16 + cr) * N + (n0 + jt[j] * 16 + cc);
#pragma unroll
            for (int r = 0; r < 4; r++) Cp[(size_t)r * N] = (OutT)acc[i][j][r];
        }
}

// ---------------------------------------------------------------- MFMA flash attention (GQA)
// block = (kvh, 16-row q tile), grid 1024 heavy-first. K/V for tile kt+1 are
// prefetched into VGPRs before compute on tile kt (loads in flight behind
// QK/softmax/PV); write phase drains them into swizzled LDS.
constexpr int VTP = 72;    // Vt row stride elems

__global__ __launch_bounds__(256, 3) void flash_attn(const __bf16* __restrict__ qkv,
                                                     __bf16* __restrict__ ob) {
    __shared__ __align__(16) __bf16 Ks[64 * 128];        // 16 KB, XOR-swizzled
    __shared__ __align__(16) __bf16 Vt[128 * VTP];       // 18 KB
    __shared__ __align__(16) __bf16 Ps[4 * 16 * 64];     // 8 KB, XOR-swizzled

    const int tid  = threadIdx.x;
    const int wave = tid >> 6, lane = tid & 63;
    const int bx   = blockIdx.x;
    const int kvh  = bx & 7;
    const int qt   = 127 - (bx >> 3);              // heavy tiles first
    const int h    = kvh * 4 + wave;
    const int r    = lane & 15, g = lane >> 4;
    const int r7   = r & 7;
    const int qglob = qt * 16 + r;

    __bf16* Pw = Ps + wave * 16 * 64;
    const __bf16* kbase = qkv + kKOff + kvh * kHD;
    const __bf16* vbase = qkv + kVOff + kvh * kHD;

    // K staging: thread covers rows kr+c*16 (c=0..3), chunk kc16; slot = kc16 ^ kr
    const int kr   = tid >> 4;      // 0..15
    const int kc16 = tid & 15;
    // V staging tasks: task = i*256+tid -> key pair p, d-chunk c
    int vp[2], vc[2];
#pragma unroll
    for (int i = 0; i < 2; i++) {
        int task = i * 256 + tid;
        vp[i] = task & 31;
        vc[i] = task >> 5;
    }

    bf16x8 qfrag[4];
    const __bf16* qrow = qkv + (size_t)(qt * 16 + r) * kQKV + h * kHD + g * 8;
#pragma unroll
    for (int c = 0; c < 4; c++) qfrag[c] = *(const bf16x8*)(qrow + c * 32);

    f32x4 o[8];
#pragma unroll
    for (int dt = 0; dt < 8; dt++) o[dt] = (f32x4)(0.f);
    float mrow = -3.0e38f, lrow = 0.f;

    const int nkt = qt / 4 + 1;

    bf16x8 kreg[4];
    bf16x8 vreg[2][2];
    auto issue = [&](int kt) {
#pragma unroll
        for (int c = 0; c < 4; c++)
            kreg[c] = *(const bf16x8*)(kbase + (size_t)(kt * 64 + kr + c * 16) * kQKV + kc16 * 8);
#pragma unroll
        for (int i = 0; i < 2; i++) {
            const __bf16* v0 = vbase + (size_t)(kt * 64 + 2 * vp[i]) * kQKV + vc[i] * 8;
            vreg[i][0] = *(const bf16x8*)v0;
            vreg[i][1] = *(const bf16x8*)(v0 + kQKV);
        }
    };

    issue(0);
    for (int kt = 0; kt < nkt; ++kt) {
        if (kt) __syncthreads();                    // prior tile's LDS reads done
        // ---- drain prefetch regs into LDS
#pragma unroll
        for (int c = 0; c < 4; c++)
            *(bf16x8*)&Ks[(kr + c * 16) * 128 + ((kc16 ^ kr) * 8)] = kreg[c];
#pragma unroll
        for (int i = 0; i < 2; i++) {
            u16x8 a = __builtin_bit_cast(u16x8, vreg[i][0]);
            u16x8 b = __builtin_bit_cast(u16x8, vreg[i][1]);
#pragma unroll
            for (int j = 0; j < 8; j++) {
                unsigned int pk = (unsigned int)a[j] | ((unsigned int)b[j] << 16);
                *(unsigned int*)(Vt + (vc[i] * 8 + j) * VTP + 2 * vp[i]) = pk;
            }
        }
        __syncthreads();
        if (kt + 1 < nkt) issue(kt + 1);            // loads fly behind compute

        // ---- S^T = K·Q^T  (Ks read honors the XOR swizzle)
        f32x4 st[4];
#pragma unroll
        for (int t = 0; t < 4; t++) st[t] = (f32x4)(0.f);
#pragma unroll
        for (int c = 0; c < 4; c++) {
#pragma unroll
            for (int t = 0; t < 4; t++) {
                bf16x8 kf = *(const bf16x8*)&Ks[(t * 16 + r) * 128 + (((c * 4 + g) ^ r) * 8)];
                st[t] = __builtin_amdgcn_mfma_f32_16x16x32_bf16(kf, qfrag[c], st[t], 0, 0, 0);
            }
        }

        // ---- causal mask: only the diagonal tile can violate
        if (kt == nkt - 1) {
#pragma unroll
            for (int t = 0; t < 4; t++)
#pragma unroll
                for (int reg = 0; reg < 4; reg++) {
                    int key = kt * 64 + t * 16 + g * 4 + reg;
                    if (key > qglob) st[t][reg] = -3.0e38f;
                }
        }

        // ---- online softmax (per q = r)
        float mloc = -3.0e38f;
#pragma unroll
        for (int t = 0; t < 4; t++)
#pragma unroll
            for (int reg = 0; reg < 4; reg++) mloc = fmaxf(mloc, st[t][reg]);
        mloc = fmaxf(mloc, __shfl_xor(mloc, 16));
        mloc = fmaxf(mloc, __shfl_xor(mloc, 32));
        float mnew  = fmaxf(mrow, mloc);
        float alpha = __expf(mrow - mnew);
        mrow = mnew;
        float lsum = 0.f;
#pragma unroll
        for (int t = 0; t < 4; t++)
#pragma unroll
            for (int reg = 0; reg < 4; reg++) {
                float pv = __expf(st[t][reg] - mnew);
                st[t][reg] = pv;
                lsum += pv;
            }
        lsum += __shfl_xor(lsum, 16);
        lsum += __shfl_xor(lsum, 32);
        lrow = lrow * alpha + lsum;

        float ar[4];
#pragma unroll
        for (int reg = 0; reg < 4; reg++) ar[reg] = __shfl(alpha, g * 4 + reg);
#pragma unroll
        for (int dt = 0; dt < 8; dt++)
#pragma unroll
            for (int reg = 0; reg < 4; reg++) o[dt][reg] *= ar[reg];

        // ---- P (bf16): C-layout -> LDS -> A-layout, XOR-swizzled 8B slots
#pragma unroll
        for (int t = 0; t < 4; t++) {
            bf16x4 pb;
#pragma unroll
            for (int j = 0; j < 4; j++) pb[j] = (__bf16)st[t][j];
            int p8 = t * 4 + g;
            *(bf16x4*)&Pw[r * 64 + (((p8 >> 1) ^ r7) * 8) + ((p8 & 1) * 4)] = pb;
        }
        __asm__ volatile("s_waitcnt lgkmcnt(0)" ::: "memory");

#pragma unroll
        for (int kc = 0; kc < 2; kc++) {
            bf16x8 pf = *(const bf16x8*)&Pw[r * 64 + (((kc * 4 + g) ^ r7) * 8)];
#pragma unroll
            for (int dt = 0; dt < 8; dt++) {
                bf16x8 vf = *(const bf16x8*)&Vt[(dt * 16 + r) * VTP + kc * 32 + g * 8];
                o[dt] = __builtin_amdgcn_mfma_f32_16x16x32_bf16(pf, vf, o[dt], 0, 0, 0);
            }
        }
    }

    // ---- epilogue
    float linv = 1.f / lrow;
    float lr4[4];
#pragma unroll
    for (int reg = 0; reg < 4; reg++) lr4[reg] = __shfl(linv, g * 4 + reg);
#pragma unroll
    for (int dt = 0; dt < 8; dt++)
#pragma unroll
        for (int reg = 0; reg < 4; reg++) {
            int qq = g * 4 + reg, dd = dt * 16 + r;
            ob[(size_t)(qt * 16 + qq) * kH + h * kHD + dd] = (__bf16)(o[dt][reg] * lr4[reg]);
        }
}

// ---------------------------------------------------------------- launch
extern "C" void kernel_launch(void* const* d_in, const int* in_sizes, int n_in,
                              void* d_out, int out_size, void* d_ws, size_t ws_size,
                              hipStream_t stream) {
    const float* x  = (const float*)d_in[0];
    const float* wq = (const float*)d_in[1];
    const float* wk = (const float*)d_in[2];
    const float* wv = (const float*)d_in[3];
    const float* wo = (const float*)d_in[4];
    float* out = (float*)d_out;

    char* p = (char*)d_ws;
    auto alloc = [&](size_t bytes) {
        char* r = p;
        p += (bytes + 255) & ~(size_t)255;
        return r;
    };
    __bf16* xb    = (__bf16*)alloc((size_t)kS * kH * 2);        // 16 MB; later attn out
    __bf16* wqkvb = (__bf16*)alloc((size_t)kQKV * kH * 2);      // 48 MB; later wo bf16
    __bf16* qkv   = (__bf16*)alloc((size_t)kS * kQKV * 2);      // 24 MB
    __bf16* ao    = xb;
    __bf16* wob   = wqkvb;

    cast_all<<<dim3(1 << 15), 256, 0, stream>>>(x, wq, wk, wv, xb, wqkvb);

    gemm_nt<__bf16, true><<<dim3(kQKV / BN, kS / BM), 256, 0, stream>>>(xb, wqkvb, qkv, kS, kQKV, kH);

    cast_bf16<<<dim3((kH * kH / 4) / 256), 256, 0, stream>>>(wo, wob, kH * kH / 4);

    flash_attn<<<dim3(kNKV * (kS / 16)), 256, 0, stream>>>(qkv, ao);

    gemm_nt<float, false><<<dim3(kH / BN, kS / BM), 256, 0, stream>>>(ao, wob, out, kS, kH, kH);
}